// Round 1
// baseline (116.565 us; speedup 1.0000x reference)
//
#include <hip/hip_runtime.h>

// RandomAttention_56573309223861
//
// Reference math:
//   probs = softmax(scores, axis=-1)            // [B,H,S,R]
//   out   = probs.sum(-1)[..., None] * v        // [B,H,S,D]
// sum(softmax(x)) == 1 exactly (to fp32 rounding ~4e-6 relative), so
// out == v. q/k/random_indices only affect the output at the ~1e-5
// absolute level, far below the 1.04e-1 harness threshold.
//
// Therefore: pure memory-bound copy of v (32 MiB) to d_out.

__global__ __launch_bounds__(256) void RandomAttention_copy_v(
    const float4* __restrict__ v, float4* __restrict__ out, int n4) {
    int i = blockIdx.x * blockDim.x + threadIdx.x;
    if (i < n4) {
        out[i] = v[i];
    }
}

extern "C" void kernel_launch(void* const* d_in, const int* in_sizes, int n_in,
                              void* d_out, int out_size, void* d_ws, size_t ws_size,
                              hipStream_t stream) {
    // setup_inputs order: q=d_in[0], k=d_in[1], v=d_in[2], random_indices=d_in[3]
    const float* v = (const float*)d_in[2];
    float* out = (float*)d_out;

    // out_size = B*H*S*D = 2*16*2048*128 = 8,388,608 (divisible by 4)
    int n4 = out_size / 4;
    const int block = 256;
    int grid = (n4 + block - 1) / block;  // 8192 blocks

    RandomAttention_copy_v<<<grid, block, 0, stream>>>(
        (const float4*)v, (float4*)out, n4);
}

// Round 2
// 116.294 us; speedup vs baseline: 1.0023x; 1.0023x over previous
//
#include <hip/hip_runtime.h>

// RandomAttention_56573309223861
//
// Reference math:
//   probs = softmax(scores, axis=-1)            // [B,H,S,R]
//   out   = probs.sum(-1)[..., None] * v        // [B,H,S,D]
// sum(softmax(x)) == 1 to fp32 rounding (~4e-6 relative), so out == v
// to ~2e-5 absolute — 4 orders of magnitude under the 1.04e-1 threshold.
// Verified passing in round 1 (absmax 0.0156 vs threshold 0.104).
//
// Round-1 profile showed our copy kernel below every 41 µs harness fill
// dispatch (absent from top-5), so the 116 µs dur_us is dominated by
// harness reset traffic. This round: use the runtime's D2D copy path
// (hipMemcpyAsync is explicitly graph-capture-safe) as the best-possible
// 32 MiB copy, to A/B whether dur_us has any kernel-side headroom left.

extern "C" void kernel_launch(void* const* d_in, const int* in_sizes, int n_in,
                              void* d_out, int out_size, void* d_ws, size_t ws_size,
                              hipStream_t stream) {
    // setup_inputs order: q=d_in[0], k=d_in[1], v=d_in[2], random_indices=d_in[3]
    const void* v = d_in[2];
    size_t bytes = (size_t)out_size * sizeof(float);  // 8,388,608 * 4 = 32 MiB
    hipMemcpyAsync(d_out, v, bytes, hipMemcpyDeviceToDevice, stream);
}